// Round 4
// baseline (552.393 us; speedup 1.0000x reference)
//
#include <hip/hip_runtime.h>
#include <hip/hip_bf16.h>
#include <stdint.h>

typedef __attribute__((ext_vector_type(8))) short bf16x8;
typedef __attribute__((ext_vector_type(4))) float f32x4;

#define NN 8192
#define DF 256
#define BM 32
#define BK 64
#define KSPLIT 2
#define KCH (NN / KSPLIT)
#define NT (KCH / BK)            // 64 tiles

static __device__ __forceinline__ unsigned short f2bf(float f) {
  union { float f; unsigned u; } v; v.f = f;
  unsigned r = (v.u + 0x7FFFu + ((v.u >> 16) & 1u)) >> 16;
  return (unsigned short)r;
}

static __device__ __forceinline__ void gl_lds16(const void* g, void* l) {
  __builtin_amdgcn_global_load_lds(
      (const __attribute__((address_space(1))) void*)g,
      (__attribute__((address_space(3))) void*)l, 16, 0, 0);
}

// ---- kernel 1: h2[j] = dot(input[j,:], A[0:256])  (one wave per row)
__global__ void k_h2(const float* __restrict__ input, const float* __restrict__ A,
                     float* __restrict__ h2) {
  int gw = (blockIdx.x * blockDim.x + threadIdx.x) >> 6;
  int lane = threadIdx.x & 63;
  float4 x = *reinterpret_cast<const float4*>(&input[(size_t)gw * DF + lane * 4]);
  float4 a = *reinterpret_cast<const float4*>(&A[lane * 4]);
  float p = x.x * a.x + x.y * a.y + x.z * a.z + x.w * a.w;
#pragma unroll
  for (int off = 32; off > 0; off >>= 1) p += __shfl_down(p, off, 64);
  if (lane == 0) h2[gw] = p;
}

// ---- kernel 2: M = max(h2)
__global__ void k_max(const float* __restrict__ h2, float* __restrict__ Mout) {
  __shared__ float sm[4];
  float m = -3.0e38f;
  for (int i = threadIdx.x; i < NN; i += 256) m = fmaxf(m, h2[i]);
#pragma unroll
  for (int off = 32; off > 0; off >>= 1) m = fmaxf(m, __shfl_down(m, off, 64));
  int lane = threadIdx.x & 63, wid = threadIdx.x >> 6;
  if (lane == 0) sm[wid] = m;
  __syncthreads();
  if (threadIdx.x == 0)
    Mout[0] = fmaxf(fmaxf(sm[0], sm[1]), fmaxf(sm[2], sm[3]));
}

// ---- kernel 3: sF (fp32) and sT (bf16)
__global__ void k_s(const float* __restrict__ h2, const float* __restrict__ Mp,
                    float* __restrict__ sF, unsigned short* __restrict__ sT) {
  int j = blockIdx.x * 256 + threadIdx.x;
  float s = expf(h2[j] - Mp[0]);
  sF[j] = s;
  sT[j] = f2bf(s);
}

// ---- kernel 4: XsT[c][j] = bf16(sF[j] * input[j][c])  plain row-major [DF][NN]
__global__ void k_xst(const float* __restrict__ input, const float* __restrict__ sF,
                      unsigned short* __restrict__ XsT) {
  int b = blockIdx.x;
  int jb = b >> 2, cb = b & 3;
  int t = threadIdx.x;
  int j0 = jb * 64 + (t & 15) * 4;
  int c0 = cb * 64 + (t >> 4) * 4;
  float4 x[4]; float s[4];
#pragma unroll
  for (int ii = 0; ii < 4; ii++) {
    x[ii] = *reinterpret_cast<const float4*>(&input[(size_t)(j0 + ii) * DF + c0]);
    s[ii] = sF[j0 + ii];
  }
#pragma unroll
  for (int q = 0; q < 4; q++) {
    ushort4 o;
    o.x = f2bf(reinterpret_cast<const float*>(&x[0])[q] * s[0]);
    o.y = f2bf(reinterpret_cast<const float*>(&x[1])[q] * s[1]);
    o.z = f2bf(reinterpret_cast<const float*>(&x[2])[q] * s[2]);
    o.w = f2bf(reinterpret_cast<const float*>(&x[3])[q] * s[3]);
    *reinterpret_cast<ushort4*>(&XsT[(size_t)(c0 + q) * NN + j0]) = o;
  }
}

// ---- kernel 5: numerator partials (+ fused denominator) via MFMA
// adj streamed through triple-buffered LDS (2-ahead, counted vmcnt, raw barrier);
// B (XsT, L2-resident) loaded directly into registers per wave.
__global__ __launch_bounds__(512, 2) void k_gemm(
    const int* __restrict__ adj, const unsigned short* __restrict__ XsT,
    const unsigned short* __restrict__ sT, float* __restrict__ C0,
    float* __restrict__ C1, float* __restrict__ denomPart) {
  __shared__ __align__(16) char Al[3][BM * BK * 4];   // 3 x 8 KB adj tiles

  const int tid = threadIdx.x;
  const int lane = tid & 63;
  const int wid = tid >> 6;
  const int wrow = wid >> 2;   // 0..1 (16 rows each)
  const int wcol = wid & 3;    // 0..3 (64 cols each)
  const int l15 = lane & 15;
  const int l4 = lane >> 4;    // 0..3

  // bijective XCD swizzle: XCDs 0-3 -> kidx 0, XCDs 4-7 -> kidx 1
  const int bx = blockIdx.x;
  const int swz = (bx & 7) * 64 + (bx >> 3);
  const int kidx = swz >> 8;
  const int rb = swz & 255;
  const int kbeg = kidx * KCH;
  float* __restrict__ Cout = kidx ? C1 : C0;

  // --- adj staging: linear LDS dest, inverse-swizzled global source (rule #21)
  const int srow = tid >> 4;                          // 0..31
  const int skb = ((tid & 15) * 16) ^ ((srow & 7) << 4);
  const int* sA = adj + (int64_t)(rb * BM + srow) * NN + kbeg + (skb >> 2);
  char* dstw = (char*)&Al[0][0] + wid * 1024;         // wave-uniform base

  // --- B fragment bases (registers, straight from L2)
  const unsigned short* Bb[4];
#pragma unroll
  for (int n = 0; n < 4; n++) {
    int c = wcol * 64 + n * 16 + l15;
    Bb[n] = XsT + (int64_t)c * NN + kbeg + l4 * 8;
  }
  const unsigned short* Sb = sT + kbeg + l4 * 8;

  // --- A-frag swizzled LDS read offsets
  const int arow_l = wrow * 16 + l15;                 // 0..31
  const int aoff = (arow_l * 256 + l4 * 32) ^ ((arow_l & 7) << 4);

  bf16x8 regB[8];
  bf16x8 sv0, sv1;
  f32x4 acc[4] = {{0,0,0,0},{0,0,0,0},{0,0,0,0},{0,0,0,0}};
  f32x4 accD = {0, 0, 0, 0};

  auto stage = [&](int t, int buf) {
    gl_lds16(sA + t * BK, dstw + buf * 8192);
  };
  auto loadB = [&](int t) {
#pragma unroll
    for (int n = 0; n < 4; n++) {
      regB[n * 2 + 0] = *reinterpret_cast<const bf16x8*>(Bb[n] + t * BK);
      regB[n * 2 + 1] = *reinterpret_cast<const bf16x8*>(Bb[n] + t * BK + 32);
    }
    sv0 = *reinterpret_cast<const bf16x8*>(Sb + t * BK);
    sv1 = *reinterpret_cast<const bf16x8*>(Sb + t * BK + 32);
  };

  // prologue: tiles 0,1 staged; B(0) in regs; full drain once
  stage(0, 0);
  stage(1, 1);
  loadB(0);
  asm volatile("s_waitcnt vmcnt(0)" ::: "memory");
  __builtin_amdgcn_s_barrier();

  int bufc = 0, bufs = 2;
  for (int t = 0; t < NT; ++t) {
    const int t2 = (t + 2 < NT) ? t + 2 : NT - 1;
    const int t1 = (t + 1 < NT) ? t + 1 : NT - 1;
    stage(t2, bufs);                       // 1 vm op (2-ahead adj prefetch)

    // ---- compute(t): A frags from LDS buf, B from regB
    const char* ab = (const char*)&Al[0][0] + bufc * 8192;
    int4 a0 = *reinterpret_cast<const int4*>(ab + (aoff));
    int4 a1 = *reinterpret_cast<const int4*>(ab + (aoff ^ 16));
    int4 a2 = *reinterpret_cast<const int4*>(ab + (aoff + 128));
    int4 a3 = *reinterpret_cast<const int4*>(ab + ((aoff + 128) ^ 16));
#pragma unroll
    for (int kk = 0; kk < 2; kk++) {
      union { unsigned u[4]; bf16x8 v; } A;
      const int4 lo = kk ? a2 : a0;
      const int4 hi = kk ? a3 : a1;
      A.u[0] = (unsigned)(lo.x + (lo.y << 16)) * 0x3F80u;
      A.u[1] = (unsigned)(lo.z + (lo.w << 16)) * 0x3F80u;
      A.u[2] = (unsigned)(hi.x + (hi.y << 16)) * 0x3F80u;
      A.u[3] = (unsigned)(hi.z + (hi.w << 16)) * 0x3F80u;
      if (wcol == 0) {
        accD = __builtin_amdgcn_mfma_f32_16x16x32_bf16(A.v, kk ? sv1 : sv0,
                                                       accD, 0, 0, 0);
      }
#pragma unroll
      for (int n = 0; n < 4; n++)
        acc[n] = __builtin_amdgcn_mfma_f32_16x16x32_bf16(A.v, regB[n * 2 + kk],
                                                         acc[n], 0, 0, 0);
    }

    loadB(t1);                             // 10 vm ops (B+sv for next tile)
    // allow this tile's 11 issues to stay in flight; waits own stage(t+1)
    asm volatile("s_waitcnt vmcnt(11)" ::: "memory");
    __builtin_amdgcn_s_barrier();

    bufc = (bufc == 2) ? 0 : bufc + 1;
    bufs = (bufs == 2) ? 0 : bufs + 1;
  }

  // epilogue: C/D layout col=lane&15, row=(lane>>4)*4+q
  const int row0 = rb * BM + wrow * 16 + l4 * 4;
#pragma unroll
  for (int n = 0; n < 4; n++) {
    int col = wcol * 64 + n * 16 + l15;
#pragma unroll
    for (int q = 0; q < 4; q++)
      Cout[(size_t)(row0 + q) * DF + col] = acc[n][q];
  }
  if (wcol == 0 && l15 == 0) {
#pragma unroll
    for (int q = 0; q < 4; q++)
      denomPart[kidx * NN + row0 + q] = accD[q];
  }
}

// ---- kernel 6: out = (C0 + C1) / denom   (in place: C0 == d_out)
__global__ void k_norm(float* __restrict__ out, const float* __restrict__ C1,
                       const float* __restrict__ denomPart) {
  int e4 = blockIdx.x * 256 + threadIdx.x;
  size_t base = (size_t)e4 * 4;
  int row = (int)(base >> 8);
  float4 a = *reinterpret_cast<const float4*>(&out[base]);
  float4 b = *reinterpret_cast<const float4*>(&C1[base]);
  float inv = 1.0f / (denomPart[row] + denomPart[NN + row]);
  float4 r;
  r.x = (a.x + b.x) * inv;
  r.y = (a.y + b.y) * inv;
  r.z = (a.z + b.z) * inv;
  r.w = (a.w + b.w) * inv;
  *reinterpret_cast<float4*>(&out[base]) = r;
}

extern "C" void kernel_launch(void* const* d_in, const int* in_sizes, int n_in,
                              void* d_out, int out_size, void* d_ws, size_t ws_size,
                              hipStream_t stream) {
  const float* input = (const float*)d_in[0];
  const int* adj = (const int*)d_in[1];
  const float* A = (const float*)d_in[2];
  float* out = (float*)d_out;

  char* ws = (char*)d_ws;
  float* h2 = (float*)(ws + 0);                         // 32 KB
  float* Mv = (float*)(ws + 32768);                     // 256 B
  float* sF = (float*)(ws + 33024);                     // 32 KB
  unsigned short* sT = (unsigned short*)(ws + 65792);   // 16 KB
  unsigned short* XsT = (unsigned short*)(ws + 82176);  // 4 MB, row-major [DF][NN]
  float* C1 = (float*)(ws + 82176 + 4194304);           // 8 MB
  float* denomPart = (float*)(ws + 82176 + 4194304 + 8388608);  // 64 KB

  k_h2<<<dim3(NN / 4), dim3(256), 0, stream>>>(input, A, h2);
  k_max<<<dim3(1), dim3(256), 0, stream>>>(h2, Mv);
  k_s<<<dim3(NN / 256), dim3(256), 0, stream>>>(h2, Mv, sF, sT);
  k_xst<<<dim3((NN / 64) * (DF / 64)), dim3(256), 0, stream>>>(input, sF, XsT);
  k_gemm<<<dim3((NN / BM) * KSPLIT), dim3(512), 0, stream>>>(adj, XsT, sT, out, C1,
                                                             denomPart);
  k_norm<<<dim3(NN * DF / 1024), dim3(256), 0, stream>>>(out, C1, denomPart);
}

// Round 5
// 450.094 us; speedup vs baseline: 1.2273x; 1.2273x over previous
//
#include <hip/hip_runtime.h>
#include <hip/hip_bf16.h>
#include <stdint.h>

typedef __attribute__((ext_vector_type(8))) short bf16x8;
typedef __attribute__((ext_vector_type(4))) float f32x4;

#define NN 8192
#define DF 256
#define BM 32
#define BK 32
#define KSPLIT 2
#define KCH (NN / KSPLIT)
#define NT (KCH / BK)              // 128 tiles per block
#define NTILES_G (NN / BK)         // 256 global B tiles
#define TILEA 4096                 // 32 rows x 32 ints
#define TILEB 16384                // 256 c x 32 k bf16 (c-paired 128B rows)
#define TILE_LDS (TILEA + TILEB)   // 20480
#define STLDS_OFF (3 * TILE_LDS)   // 61440
#define LDS_TOTAL (STLDS_OFF + 8192)

static __device__ __forceinline__ unsigned short f2bf(float f) {
  union { float f; unsigned u; } v; v.f = f;
  unsigned r = (v.u + 0x7FFFu + ((v.u >> 16) & 1u)) >> 16;
  return (unsigned short)r;
}

static __device__ __forceinline__ void gl_lds16(const void* g, void* l) {
  __builtin_amdgcn_global_load_lds(
      (const __attribute__((address_space(1))) void*)g,
      (__attribute__((address_space(3))) void*)l, 16, 0, 0);
}

// ---- kernel 1: h2[j] = dot(input[j,:], A[0:256])  (one wave per row)
__global__ void k_h2(const float* __restrict__ input, const float* __restrict__ A,
                     float* __restrict__ h2) {
  int gw = (blockIdx.x * blockDim.x + threadIdx.x) >> 6;
  int lane = threadIdx.x & 63;
  float4 x = *reinterpret_cast<const float4*>(&input[(size_t)gw * DF + lane * 4]);
  float4 a = *reinterpret_cast<const float4*>(&A[lane * 4]);
  float p = x.x * a.x + x.y * a.y + x.z * a.z + x.w * a.w;
#pragma unroll
  for (int off = 32; off > 0; off >>= 1) p += __shfl_down(p, off, 64);
  if (lane == 0) h2[gw] = p;
}

// ---- kernel 2: per-block global max (redundant) + s = exp(h2 - M), fp32+bf16
__global__ void k_s(const float* __restrict__ h2, float* __restrict__ sF,
                    unsigned short* __restrict__ sT) {
  __shared__ float sm[4];
  float m = -3.0e38f;
  for (int i = threadIdx.x; i < NN; i += 256) m = fmaxf(m, h2[i]);
#pragma unroll
  for (int off = 32; off > 0; off >>= 1) m = fmaxf(m, __shfl_down(m, off, 64));
  int lane = threadIdx.x & 63, wid = threadIdx.x >> 6;
  if (lane == 0) sm[wid] = m;
  __syncthreads();
  float M = fmaxf(fmaxf(sm[0], sm[1]), fmaxf(sm[2], sm[3]));
  int j = blockIdx.x * 256 + threadIdx.x;
  float s = expf(h2[j] - M);
  sF[j] = s;
  sT[j] = f2bf(s);
}

// ---- kernel 3: XsT pre-swizzled tiled layout (linear image of the LDS B tile)
// Element (c, j): tile = j>>5, addr = tile*TILEB + (c&127)*128 + (c>>7)*64
//                 + (((j&31)*2) ^ ((c&3)<<4))
__global__ void k_xst(const float* __restrict__ input, const float* __restrict__ sF,
                      char* __restrict__ XsTb) {
  int b = blockIdx.x;
  int jb = b >> 2, cb = b & 3;
  int t = threadIdx.x;
  int j0 = jb * 64 + (t & 15) * 4;
  int c0 = cb * 64 + (t >> 4) * 4;
  float4 x[4]; float s[4];
#pragma unroll
  for (int ii = 0; ii < 4; ii++) {
    x[ii] = *reinterpret_cast<const float4*>(&input[(size_t)(j0 + ii) * DF + c0]);
    s[ii] = sF[j0 + ii];
  }
#pragma unroll
  for (int q = 0; q < 4; q++) {
    int c = c0 + q;
    ushort4 o;
    o.x = f2bf(reinterpret_cast<const float*>(&x[0])[q] * s[0]);
    o.y = f2bf(reinterpret_cast<const float*>(&x[1])[q] * s[1]);
    o.z = f2bf(reinterpret_cast<const float*>(&x[2])[q] * s[2]);
    o.w = f2bf(reinterpret_cast<const float*>(&x[3])[q] * s[3]);
    size_t addr = (size_t)(j0 >> 5) * TILEB + (c & 127) * 128 + (c >> 7) * 64 +
                  (((j0 & 31) * 2) ^ ((c & 3) << 4));
    *reinterpret_cast<ushort4*>(XsTb + addr) = o;
  }
}

// ---- kernel 4: numerator partials (+ fused denominator) via MFMA.
// Triple-buffered LDS staging via global_load_lds, 2 tiles ahead, counted vmcnt(5).
__global__ __launch_bounds__(256, 2) void k_gemm(
    const int* __restrict__ adj, const char* __restrict__ XsTb,
    const unsigned short* __restrict__ sT, float* __restrict__ C0,
    float* __restrict__ C1, float* __restrict__ denomPart) {
  __shared__ __align__(16) char lds[LDS_TOTAL];

  const int tid = threadIdx.x;
  const int lane = tid & 63;
  const int wid = tid >> 6;       // 4 waves: each owns 64 output cols
  const int l15 = lane & 15;
  const int l4 = lane >> 4;       // 0..3

  // bijective XCD swizzle: 512 wgs -> 64/XCD; XCDs 0-3 kidx 0, 4-7 kidx 1
  const int bx = blockIdx.x;
  const int swz = (bx & 7) * 64 + (bx >> 3);
  const int kidx = swz >> 8;
  const int rb = swz & 255;
  const int kbeg = kidx * KCH;
  const int kt0 = kidx * NT;
  float* __restrict__ Cout = kidx ? C1 : C0;

  // --- staging source bases (per thread)
  // A: LDS linear t*16 <-> (row = t>>3, chunk (t&7)*16 ^ ((row&7)<<4))
  const int srow = tid >> 3;
  const int sbyte = ((tid & 7) * 16) ^ ((srow & 7) << 4);
  const char* pA = (const char*)adj +
                   ((size_t)(rb * BM + srow) * NN + kbeg) * 4 + sbyte;
  const char* pB = XsTb + (size_t)kt0 * TILEB + tid * 16;
  const char* pS = (const char*)sT + (size_t)kbeg * 2 + tid * 16;
  char* dstT = lds + tid * 16;

  // --- compute-side addresses
  const int arow0 = l15;                    // frag m: row = m*16 + l15
  int aoff[2];
#pragma unroll
  for (int m = 0; m < 2; m++) {
    int row = m * 16 + arow0;
    aoff[m] = row * 128 + ((l4 * 32) ^ ((row & 7) << 4));
  }
  int boff[4];
#pragma unroll
  for (int n = 0; n < 4; n++) {
    int c = wid * 64 + n * 16 + l15;
    boff[n] = (c & 127) * 128 + ((c >> 7) << 6) + ((l4 * 16) ^ ((c & 3) << 4));
  }
  const char* sTl = lds + STLDS_OFF + l4 * 16;

  f32x4 acc[2][4] = {{{0,0,0,0},{0,0,0,0},{0,0,0,0},{0,0,0,0}},
                     {{0,0,0,0},{0,0,0,0},{0,0,0,0},{0,0,0,0}}};
  f32x4 accD[2] = {{0,0,0,0},{0,0,0,0}};

  auto stage = [&](int tk, int buf) {
    char* d = dstT + buf * TILE_LDS;
    gl_lds16(pA + (size_t)tk * 128, d);                      // A: 4 KB
#pragma unroll
    for (int o = 0; o < 4; o++)                              // B: 16 KB
      gl_lds16(pB + (size_t)tk * TILEB + o * 4096, d + TILEA + o * 4096);
  };

  // prologue: stage sT chunk (2 ops) + tiles 0,1 (5+5); wait keeps tile1 flying
  gl_lds16(pS, lds + STLDS_OFF + tid * 16);
  gl_lds16(pS + 4096, lds + STLDS_OFF + 4096 + tid * 16);
  stage(0, 0);
  stage(1, 1);
  asm volatile("s_waitcnt vmcnt(5)" ::: "memory");
  __builtin_amdgcn_s_barrier();

  int bcur = 0, bnx2 = 2;
  for (int t = 0; t < NT; ++t) {
    const int tk2 = (t + 2 < NT) ? t + 2 : NT - 1;
    stage(tk2, bnx2);

    // ---- compute tile t from buffer bcur
    const char* ab = lds + bcur * TILE_LDS;
    const char* bb = ab + TILEA;
    bf16x8 Am[2];
#pragma unroll
    for (int m = 0; m < 2; m++) {
      int4 lo = *reinterpret_cast<const int4*>(ab + aoff[m]);
      int4 hi = *reinterpret_cast<const int4*>(ab + (aoff[m] ^ 16));
      union { unsigned u[4]; bf16x8 v; } A;
      A.u[0] = (unsigned)(lo.x + (lo.y << 16)) * 0x3F80u;
      A.u[1] = (unsigned)(lo.z + (lo.w << 16)) * 0x3F80u;
      A.u[2] = (unsigned)(hi.x + (hi.y << 16)) * 0x3F80u;
      A.u[3] = (unsigned)(hi.z + (hi.w << 16)) * 0x3F80u;
      Am[m] = A.v;
    }
    bf16x8 sv = *reinterpret_cast<const bf16x8*>(sTl + t * 64);
#pragma unroll
    for (int n = 0; n < 4; n++) {
      bf16x8 Bf = *reinterpret_cast<const bf16x8*>(bb + boff[n]);
#pragma unroll
      for (int m = 0; m < 2; m++)
        acc[m][n] = __builtin_amdgcn_mfma_f32_16x16x32_bf16(Am[m], Bf,
                                                            acc[m][n], 0, 0, 0);
    }
#pragma unroll
    for (int m = 0; m < 2; m++)
      accD[m] = __builtin_amdgcn_mfma_f32_16x16x32_bf16(Am[m], sv,
                                                        accD[m], 0, 0, 0);

    asm volatile("s_waitcnt vmcnt(5)" ::: "memory");
    __builtin_amdgcn_s_barrier();
    bcur = (bcur == 2) ? 0 : bcur + 1;
    bnx2 = (bnx2 == 2) ? 0 : bnx2 + 1;
  }

  // epilogue: C/D layout col = lane&15, row = (lane>>4)*4 + q
#pragma unroll
  for (int m = 0; m < 2; m++) {
    int row0 = rb * BM + m * 16 + l4 * 4;
#pragma unroll
    for (int n = 0; n < 4; n++) {
      int col = wid * 64 + n * 16 + l15;
#pragma unroll
      for (int q = 0; q < 4; q++)
        Cout[(size_t)(row0 + q) * DF + col] = acc[m][n][q];
    }
    if (wid == 0 && l15 == 0) {
#pragma unroll
      for (int q = 0; q < 4; q++)
        denomPart[kidx * NN + row0 + q] = accD[m][q];
    }
  }
}

// ---- kernel 5: out = (C0 + C1) / denom   (in place: C0 == d_out)
__global__ void k_norm(float* __restrict__ out, const float* __restrict__ C1,
                       const float* __restrict__ denomPart) {
  int e4 = blockIdx.x * 256 + threadIdx.x;
  size_t base = (size_t)e4 * 4;
  int row = (int)(base >> 8);
  float4 a = *reinterpret_cast<const float4*>(&out[base]);
  float4 b = *reinterpret_cast<const float4*>(&C1[base]);
  float inv = 1.0f / (denomPart[row] + denomPart[NN + row]);
  float4 r;
  r.x = (a.x + b.x) * inv;
  r.y = (a.y + b.y) * inv;
  r.z = (a.z + b.z) * inv;
  r.w = (a.w + b.w) * inv;
  *reinterpret_cast<float4*>(&out[base]) = r;
}

extern "C" void kernel_launch(void* const* d_in, const int* in_sizes, int n_in,
                              void* d_out, int out_size, void* d_ws, size_t ws_size,
                              hipStream_t stream) {
  const float* input = (const float*)d_in[0];
  const int* adj = (const int*)d_in[1];
  const float* A = (const float*)d_in[2];
  float* out = (float*)d_out;

  char* ws = (char*)d_ws;
  float* h2 = (float*)(ws + 0);                         // 32 KB
  float* sF = (float*)(ws + 33024);                     // 32 KB
  unsigned short* sT = (unsigned short*)(ws + 65792);   // 16 KB
  char* XsTb = (char*)(ws + 82176);                     // 4 MB tiled/swizzled
  float* C1 = (float*)(ws + 82176 + 4194304);           // 8 MB
  float* denomPart = (float*)(ws + 82176 + 4194304 + 8388608);  // 64 KB

  k_h2<<<dim3(NN / 4), dim3(256), 0, stream>>>(input, A, h2);
  k_s<<<dim3(NN / 256), dim3(256), 0, stream>>>(h2, sF, sT);
  k_xst<<<dim3((NN / 64) * (DF / 64)), dim3(256), 0, stream>>>(input, sF, XsTb);
  k_gemm<<<dim3((NN / BM) * KSPLIT), dim3(256), 0, stream>>>(adj, XsTb, sT, out, C1,
                                                             denomPart);
  k_norm<<<dim3(NN * DF / 1024), dim3(256), 0, stream>>>(out, C1, denomPart);
}